// Round 1
// baseline (281.086 us; speedup 1.0000x reference)
//
#include <hip/hip_runtime.h>
#include <hip/hip_cooperative_groups.h>

namespace cg = cooperative_groups;

#define CMIN -1024.0f
#define CMAX 1016.0f

__device__ __forceinline__ float clampv(float x) {
    return fminf(fmaxf(x, CMIN), CMAX);
}

__device__ __forceinline__ float wave_reduce(float v) {
    #pragma unroll
    for (int off = 32; off > 0; off >>= 1)
        v += __shfl_down(v, off, 64);
    return v;
}

// ---------------------------------------------------------------------------
// Single cooperative kernel:
//   Phase A: y elementwise (96 MiB of the 201 MB payload) + scattered DC
//            gather of c, block-reduced to ws[blockIdx.x] (no atomics, no
//            memset needed: readers only touch ws[0..511], all written).
//   grid.sync()
//   Phase B: every block re-reduces the 512 partials (1 KB from L2) to get
//            both channel means, then c elementwise with DC adjustment.
//
// Grid: 1024 blocks x 256 threads = 262144 threads; cooperative launch needs
// only 4 blocks/CU co-resident (safe for this register footprint).
// DC partial layout invariant: block b < 512 covers DCs [b*256, b*256+255],
// entirely inside one channel (65536 DC/ch / 256 = 256 blocks/ch).
// ---------------------------------------------------------------------------
__global__ void __launch_bounds__(256)
fused_all(const float4* __restrict__ y4, const float* __restrict__ c,
          const float4* __restrict__ c4, float4* __restrict__ out,
          float* __restrict__ ws, int ynvec, int cnvec, int c_half_nvec,
          int dc_count, float neg09_inv_count)
{
    const int tid = blockIdx.x * blockDim.x + threadIdx.x;
    const int T   = gridDim.x * blockDim.x;
    const int lane = threadIdx.x & 63;
    const int wave = threadIdx.x >> 6;
    __shared__ float smem[8];

    // ---- Phase A ----
    // Issue the scattered DC load first; its waitcnt lands after the y-loop
    // (independent), so the ~200-900 cy latency hides under the y stream.
    float dcv = 0.0f;
    if (tid < dc_count) dcv = clampv(c[(size_t)tid * 64]);

    for (int i = tid; i < ynvec; i += T) {
        float4 v = y4[i];
        v.x = clampv(clampv(v.x) * 1.9f);
        v.y = clampv(clampv(v.y) * 1.9f);
        v.z = clampv(clampv(v.z) * 1.9f);
        v.w = clampv(clampv(v.w) * 1.9f);
        out[i] = v;
    }

    // Block-reduce the DC partial -> ws[blockIdx.x]  (blocks >= 512 write 0;
    // phase B only reads ws[0..511]).
    float s = wave_reduce(dcv);
    if (lane == 0) smem[wave] = s;
    __syncthreads();
    if (threadIdx.x == 0)
        ws[blockIdx.x] = smem[0] + smem[1] + smem[2] + smem[3];

    cg::this_grid().sync();

    // ---- Phase B ----
    // Every block recomputes both channel sums from the 512 partials
    // (1 KB, L2-resident broadcast) -- avoids a second grid sync.
    float p0 = wave_reduce(ws[threadIdx.x]);        // ch0: blocks 0..255
    float p1 = wave_reduce(ws[256 + threadIdx.x]);  // ch1: blocks 256..511
    if (lane == 0) { smem[wave] = p0; smem[4 + wave] = p1; }
    __syncthreads();
    if (threadIdx.x == 0) {
        smem[0] = (smem[0] + smem[1] + smem[2] + smem[3]) * neg09_inv_count;
        smem[4] = (smem[4] + smem[5] + smem[6] + smem[7]) * neg09_inv_count;
    }
    __syncthreads();
    const float adj0 = smem[0];  // -0.9 * dc_mean[ch]
    const float adj1 = smem[4];

    float4* outc = out + ynvec;
    for (int i = tid; i < cnvec; i += T) {
        float4 v = c4[i];
        float4 r;
        r.x = clampv(v.x) * 1.9f;
        r.y = clampv(v.y) * 1.9f;
        r.z = clampv(v.z) * 1.9f;
        r.w = clampv(v.w) * 1.9f;
        if ((i & 15) == 0)                       // DC element of its 8x8 block
            r.x += (i < c_half_nvec) ? adj0 : adj1;
        r.x = clampv(r.x);
        r.y = clampv(r.y);
        r.z = clampv(r.z);
        r.w = clampv(r.w);
        outc[i] = r;
    }
}

extern "C" void kernel_launch(void* const* d_in, const int* in_sizes, int n_in,
                              void* d_out, int out_size, void* d_ws, size_t ws_size,
                              hipStream_t stream) {
    const float* y = (const float*)d_in[0];
    const float* c = (const float*)d_in[1];
    float* out = (float*)d_out;
    float* ws  = (float*)d_ws;

    const int yN = in_sizes[0];             // 16777216 floats
    const int cN = in_sizes[1];             // 8388608 floats

    int ynvec       = yN / 4;               // 4194304 float4
    int cnvec       = cN / 4;               // 2097152 float4
    int c_half_nvec = cnvec / 2;            // 1048576
    int dc_count    = cN / 64;              // 131072
    float neg09_inv_count = -0.9f / (float)(dc_count / 2);

    const float4* y4 = (const float4*)y;
    const float4* c4 = (const float4*)c;

    void* args[] = {(void*)&y4, (void*)&c, (void*)&c4, (void*)&out,
                    (void*)&ws, (void*)&ynvec, (void*)&cnvec,
                    (void*)&c_half_nvec, (void*)&dc_count,
                    (void*)&neg09_inv_count};

    hipLaunchCooperativeKernel((void*)fused_all, dim3(1024), dim3(256),
                               args, 0, stream);
}

// Round 2
// 180.596 us; speedup vs baseline: 1.5564x; 1.5564x over previous
//
#include <hip/hip_runtime.h>

#define CMIN -1024.0f
#define CMAX 1016.0f

__device__ __forceinline__ float clampv(float x) {
    return fminf(fmaxf(x, CMIN), CMAX);
}

__device__ __forceinline__ float wave_reduce(float v) {
    #pragma unroll
    for (int off = 32; off > 0; off >>= 1)
        v += __shfl_down(v, off, 64);
    return v;
}

// ---------------------------------------------------------------------------
// Kernel 1: y elementwise (one float4/thread, one-shot grid) + DC partial sums.
//   - DC gather c[tid*64] issues FIRST; independent of the y stream, so its
//     ~900 cy latency hides under the y float4 load/store.
//   - Blocks 0..511 (tid 0..131071) exactly cover the 131072 DC coefficients;
//     each writes a non-atomic partial to ws[blockIdx.x]. No memset, no
//     atomics, deterministic.
// ---------------------------------------------------------------------------
__global__ void __launch_bounds__(256)
y_and_dc(const float4* __restrict__ y4, const float* __restrict__ c,
         float4* __restrict__ out, float* __restrict__ ws,
         int ynvec, int dc_count)
{
    const int tid = blockIdx.x * blockDim.x + threadIdx.x;
    __shared__ float smem[4];

    // scattered DC gather (blocks 0..511 only are fully active here)
    float dcv = 0.0f;
    if (tid < dc_count) dcv = clampv(c[(size_t)tid * 64]);

    // y elementwise: out = clamp(clamp(y) * 1.9)
    if (tid < ynvec) {
        float4 v = y4[tid];
        v.x = clampv(clampv(v.x) * 1.9f);
        v.y = clampv(clampv(v.y) * 1.9f);
        v.z = clampv(clampv(v.z) * 1.9f);
        v.w = clampv(clampv(v.w) * 1.9f);
        out[tid] = v;
    }

    // block-reduce DC partial -> ws[blockIdx.x]  (blocks 0..dc_count/256-1)
    if (blockIdx.x < (dc_count >> 8)) {
        float s = wave_reduce(dcv);
        const int lane = threadIdx.x & 63;
        const int wave = threadIdx.x >> 6;
        if (lane == 0) smem[wave] = s;
        __syncthreads();
        if (threadIdx.x == 0)
            ws[blockIdx.x] = smem[0] + smem[1] + smem[2] + smem[3];
    }
}

// ---------------------------------------------------------------------------
// Kernel 2: c elementwise with DC-mean adjustment.
//   Prologue: each block re-reduces the 512 partials (2 KB, L2-resident
//   broadcast) to both channel adjustments. The c4 payload load is issued
//   BEFORE the prologue so HBM latency overlaps the reduce.
//   ws layout: ws[0..255] = ch0 partials, ws[256..511] = ch1 partials.
// ---------------------------------------------------------------------------
__global__ void __launch_bounds__(256)
c_elementwise(const float4* __restrict__ c4, float4* __restrict__ outc,
              const float* __restrict__ ws, int cnvec, int c_half_nvec,
              float neg09_inv_count)
{
    const int i = blockIdx.x * blockDim.x + threadIdx.x;
    __shared__ float sm[8];
    __shared__ float sadj[2];

    // issue payload load first (hides under the prologue reduce)
    float4 v;
    if (i < cnvec) v = c4[i];

    // prologue: both channel sums from the 512 partials
    float s0 = wave_reduce(ws[threadIdx.x]);
    float s1 = wave_reduce(ws[256 + threadIdx.x]);
    const int lane = threadIdx.x & 63;
    const int wave = threadIdx.x >> 6;
    if (lane == 0) { sm[wave] = s0; sm[4 + wave] = s1; }
    __syncthreads();
    if (threadIdx.x == 0) {
        sadj[0] = (sm[0] + sm[1] + sm[2] + sm[3]) * neg09_inv_count;
        sadj[1] = (sm[4] + sm[5] + sm[6] + sm[7]) * neg09_inv_count;
    }
    __syncthreads();

    if (i < cnvec) {
        float4 r;
        r.x = clampv(v.x) * 1.9f;
        r.y = clampv(v.y) * 1.9f;
        r.z = clampv(v.z) * 1.9f;
        r.w = clampv(v.w) * 1.9f;
        if ((i & 15) == 0)                        // DC element of its 8x8 block
            r.x += (i < c_half_nvec) ? sadj[0] : sadj[1];
        r.x = clampv(r.x);
        r.y = clampv(r.y);
        r.z = clampv(r.z);
        r.w = clampv(r.w);
        outc[i] = r;
    }
}

extern "C" void kernel_launch(void* const* d_in, const int* in_sizes, int n_in,
                              void* d_out, int out_size, void* d_ws, size_t ws_size,
                              hipStream_t stream) {
    const float* y = (const float*)d_in[0];
    const float* c = (const float*)d_in[1];
    float* out = (float*)d_out;
    float* ws  = (float*)d_ws;

    const int yN = in_sizes[0];             // 16777216 floats
    const int cN = in_sizes[1];             // 8388608 floats

    const int ynvec       = yN / 4;         // 4194304 float4
    const int cnvec       = cN / 4;         // 2097152 float4
    const int c_half_nvec = cnvec / 2;      // 1048576
    const int dc_count    = cN / 64;        // 131072  (=> 512 partial blocks)
    const float neg09_inv_count = -0.9f / (float)(dc_count / 2);

    // Kernel 1: y stream + DC partials (one-shot grid, proven-fast shape)
    y_and_dc<<<(ynvec + 255) / 256, 256, 0, stream>>>(
        (const float4*)y, c, (float4*)out, ws, ynvec, dc_count);

    // Kernel 2: c stream + DC adjustment
    c_elementwise<<<(cnvec + 255) / 256, 256, 0, stream>>>(
        (const float4*)c, (float4*)out + ynvec, ws, cnvec, c_half_nvec,
        neg09_inv_count);
}